// Round 18
// baseline (549.126 us; speedup 1.0000x reference)
//
#include <hip/hip_runtime.h>

#define ROWS 8192   // B*T
#define DD   1024   // d_model
#define TT   2048   // T
#define NH   16     // heads
#define HS   64     // head size
#define CH   32     // scan chunk length
#define NC   (TT / CH)   // 64 chunks

typedef __attribute__((ext_vector_type(8))) short short8;
typedef __attribute__((ext_vector_type(4))) float f32x4;
typedef __attribute__((ext_vector_type(4))) unsigned short us4;
typedef unsigned short u16;

__device__ __forceinline__ u16 f2bf(float f) {
  unsigned u = __builtin_bit_cast(unsigned, f);
  u += 0x7fffu + ((u >> 16) & 1u);   // round-to-nearest-even
  return (u16)(u >> 16);
}

__device__ __forceinline__ float bf2f(u16 h) {
  return __builtin_bit_cast(float, (unsigned)h << 16);
}

__device__ __forceinline__ void gload16(const void* g, void* l) {
  __builtin_amdgcn_global_load_lds(
      (const __attribute__((address_space(1))) unsigned int*)g,
      (__attribute__((address_space(3))) unsigned int*)l, 16, 0, 0);
}

// ---------------- transpose + cast to bf16: WT[n][k] = bf16(W[k][n]) ----------------
__global__ __launch_bounds__(256) void transpose_cast(const float* __restrict__ W,
                                                      u16* __restrict__ WT) {
  __shared__ float tile[32][33];
  const int tx = threadIdx.x, ty = threadIdx.y;
  const int bx = blockIdx.x, by = blockIdx.y;
#pragma unroll
  for (int j = 0; j < 4; ++j)
    tile[ty + j * 8][tx] = W[(size_t)(by * 32 + ty + j * 8) * DD + bx * 32 + tx];
  __syncthreads();
#pragma unroll
  for (int j = 0; j < 4; ++j)
    WT[(size_t)(bx * 32 + ty + j * 8) * DD + by * 32 + tx] = f2bf(tile[tx][ty + j * 8]);
}

// ---------------- LayerNorm (pop. variance) + cast to bf16 ----------------
__global__ __launch_bounds__(256) void ln_kernel(const float* __restrict__ x,
                                                 const float* __restrict__ g,
                                                 const float* __restrict__ b,
                                                 u16* __restrict__ xn) {
  const int row = blockIdx.x;
  const int tid = threadIdx.x;
  const float4 v = reinterpret_cast<const float4*>(x + (size_t)row * DD)[tid];
  float s = v.x + v.y + v.z + v.w;
  float s2 = v.x * v.x + v.y * v.y + v.z * v.z + v.w * v.w;
#pragma unroll
  for (int o = 32; o > 0; o >>= 1) { s += __shfl_down(s, o); s2 += __shfl_down(s2, o); }
  __shared__ float red[8];
  const int wv = tid >> 6;
  if ((tid & 63) == 0) { red[wv] = s; red[4 + wv] = s2; }
  __syncthreads();
  s = red[0] + red[1] + red[2] + red[3];
  s2 = red[4] + red[5] + red[6] + red[7];
  const float mu = s * (1.f / 1024.f);
  const float var = s2 * (1.f / 1024.f) - mu * mu;
  const float rstd = rsqrtf(var + 1e-5f);
  const float4 gg = reinterpret_cast<const float4*>(g)[tid];
  const float4 bb = reinterpret_cast<const float4*>(b)[tid];
  us4 o4;
  o4.x = f2bf((v.x - mu) * rstd * gg.x + bb.x);
  o4.y = f2bf((v.y - mu) * rstd * gg.y + bb.y);
  o4.z = f2bf((v.z - mu) * rstd * gg.z + bb.z);
  o4.w = f2bf((v.w - mu) * rstd * gg.w + bb.w);
  *reinterpret_cast<us4*>(xn + (size_t)row * DD + tid * 4) = o4;
}

// ---------------- bf16 MFMA GEMM: C = A(MxK) @ BT(NxK)^T, epilogue per EPI ----------------
// EPI: 0 = store bf16, 1 = store f32, 2 = sigmoid bf16, 3 = bias + (1-sigmoid) bf16
template <int EPI>
__global__ __launch_bounds__(256) void gemm_bt(const u16* __restrict__ A,
                                               const u16* __restrict__ BT,
                                               float* __restrict__ Cf,
                                               u16* __restrict__ Cb,
                                               const float* __restrict__ bias,
                                               int M, int N, int K) {
  __shared__ u16 lA[2][128 * 32];
  __shared__ u16 lB[2][128 * 32];
  const int tid = threadIdx.x;
  const int bx = blockIdx.x, by = blockIdx.y;
  const int lane = tid & 63, wid = tid >> 6;
  const int wr = wid >> 1, wc = wid & 1;
  const int sr = tid >> 2, sc = (tid & 3) * 8;
  const u16* gA = A + (size_t)(by * 128 + sr) * K + sc;
  const u16* gB = BT + (size_t)(bx * 128 + sr) * K + sc;

  f32x4 acc[4][4];
#pragma unroll
  for (int m = 0; m < 4; ++m)
#pragma unroll
    for (int n = 0; n < 4; ++n) acc[m][n] = (f32x4){0.f, 0.f, 0.f, 0.f};

  auto stage = [&](int buf, int kt) {
    const u16* a0 = gA + kt * 32;
    const u16* b0 = gB + kt * 32;
    gload16(a0, &lA[buf][tid * 8]);
    gload16(a0 + (size_t)64 * K, &lA[buf][2048 + tid * 8]);
    gload16(b0, &lB[buf][tid * 8]);
    gload16(b0 + (size_t)64 * K, &lB[buf][2048 + tid * 8]);
  };

  stage(0, 0);
  const int fr = lane & 15, fk = (lane >> 4) * 8;
  int cur = 0;
  const int nk = K / 32;
  for (int kt = 0; kt < nk; ++kt) {
    __syncthreads();
    if (kt + 1 < nk) stage(cur ^ 1, kt + 1);
    short8 af[4], bv[4];
#pragma unroll
    for (int m = 0; m < 4; ++m)
      af[m] = *reinterpret_cast<const short8*>(&lA[cur][(wr * 64 + m * 16 + fr) * 32 + fk]);
#pragma unroll
    for (int n = 0; n < 4; ++n)
      bv[n] = *reinterpret_cast<const short8*>(&lB[cur][(wc * 64 + n * 16 + fr) * 32 + fk]);
#pragma unroll
    for (int m = 0; m < 4; ++m)
#pragma unroll
      for (int n = 0; n < 4; ++n)
        acc[m][n] = __builtin_amdgcn_mfma_f32_16x16x32_bf16(af[m], bv[n], acc[m][n], 0, 0, 0);
    cur ^= 1;
  }

  const int er = (lane >> 4) * 4, ec = lane & 15;
#pragma unroll
  for (int m = 0; m < 4; ++m) {
    const int row0 = by * 128 + wr * 64 + m * 16 + er;
#pragma unroll
    for (int n = 0; n < 4; ++n) {
      const int col = bx * 128 + wc * 64 + n * 16 + ec;
#pragma unroll
      for (int i = 0; i < 4; ++i) {
        const float val = acc[m][n][i];
        const size_t idx = (size_t)(row0 + i) * N + col;
        if constexpr (EPI == 0) {
          Cb[idx] = f2bf(val);
        } else if constexpr (EPI == 1) {
          Cf[idx] = val;
        } else if constexpr (EPI == 2) {
          Cb[idx] = f2bf(1.f / (1.f + __expf(-val)));
        } else {
          const float z = val + bias[col];
          Cb[idx] = f2bf(1.f / (1.f + __expf(z)));   // 1 - sigmoid(z)
        }
      }
    }
  }
}

// ---------------- chunked scan, phase 1 ----------------
// grid (NC, 64 chains), 256 threads = 4 waves; wave w owns d in [16w,16w+16).
// bf16 op/kp/vv staged per 16-step window into LDS (double-buffered, global_load_lds).
__global__ __launch_bounds__(256) void scan_phase1(const u16* __restrict__ omw,
                                                   const u16* __restrict__ kk,
                                                   const u16* __restrict__ vv,
                                                   u16* __restrict__ U,
                                                   float* __restrict__ P) {
  __shared__ u16 win[2 * 3072];              // 2 bufs x {op,kp,vv} x 16 x 64 bf16 = 12 KB
  const int c = blockIdx.x, bh = blockIdx.y;
  const int tid = threadIdx.x;
  const int lane = tid & 63;
  const int wid = tid >> 6;
  const int dbase = __builtin_amdgcn_readfirstlane(wid << 4);
  const size_t chainBase = (size_t)(bh >> 4) * TT * DD + (size_t)(bh & 15) * HS;
  const size_t base0 = chainBase + (size_t)c * CH * DD;

  auto stage = [&](int buf, int w2) {
#pragma unroll
    for (int j = 0; j < 2; ++j) {
      const int idx = tid + 256 * j;          // [0,384): (a, tt, seg of 8 bf16)
      if (idx < 384) {
        const int a = idx >> 7, rem = idx & 127, tt = rem >> 3, seg = rem & 7;
        const u16* s = (a == 0) ? omw : (a == 1) ? kk : vv;
        gload16(s + base0 + (size_t)(w2 * 16 + tt) * DD + seg * 8,
                &win[buf * 3072 + idx * 8]);  // dest = wave-uniform base + lane*16
      }
    }
  };

  float st[16];
#pragma unroll
  for (int i = 0; i < 16; ++i) st[i] = 0.f;
  const int pd = dbase + (lane & 15);
  float vp = 1.f;

  stage(0, 0);
  __syncthreads();
  int buf = 0;
  for (int w2 = 0; w2 < CH / 16; ++w2) {
    if (w2 + 1 < CH / 16) stage(buf ^ 1, w2 + 1);
    const u16* wb = &win[buf * 3072];
#pragma unroll
    for (int tt = 0; tt < 16; ++tt) {
      const short8 o8a = *(const short8*)&wb[       tt * 64 + dbase];      // broadcast
      const short8 o8b = *(const short8*)&wb[       tt * 64 + dbase + 8];
      const short8 k8a = *(const short8*)&wb[1024 + tt * 64 + dbase];
      const short8 k8b = *(const short8*)&wb[1024 + tt * 64 + dbase + 8];
      const float ve  = bf2f(wb[2048 + tt * 64 + lane]);                   // per-lane
      vp *= bf2f(wb[tt * 64 + pd]);
#pragma unroll
      for (int i = 0; i < 8; ++i) {
        st[i]     = __builtin_fmaf(bf2f((u16)o8a[i]), st[i],     bf2f((u16)k8a[i]) * ve);
        st[8 + i] = __builtin_fmaf(bf2f((u16)o8b[i]), st[8 + i], bf2f((u16)k8b[i]) * ve);
      }
    }
    __syncthreads();
    buf ^= 1;
  }
  u16* __restrict__ Ub = U + ((size_t)c * 64 + bh) * 4096;
#pragma unroll
  for (int i = 0; i < 16; ++i) Ub[(dbase + i) * 64 + lane] = f2bf(st[i]);
  if (lane < 16) P[((size_t)c * 64 + bh) * 64 + dbase + lane] = vp;
}

// ---------------- phase 2: sequential combine over chunks (in-place: U becomes S_start) ----
// grid (64 chains, 16 d-slices), 256 threads; thread owns one (d,e) element; fp32 accum
__global__ __launch_bounds__(256) void scan_phase2(u16* __restrict__ U,
                                                   const float* __restrict__ P,
                                                   float* __restrict__ stateOut) {
  const int bh = blockIdx.x;
  const int ds = blockIdx.y;
  const int tid = threadIdx.x;
  const int d = ds * 4 + (tid >> 6);   // wave-uniform
  const int e = tid & 63;
  const size_t el = (size_t)d * 64 + e;

  float S = 0.f;
  size_t ub = (size_t)bh * 4096 + el;
  size_t pb = (size_t)bh * 64 + d;
  u16 u_c = U[ub];
  float p_c = P[pb];
  for (int c = 0; c < NC; ++c) {
    u16 u_n = u_c; float p_n = p_c;
    if (c + 1 < NC) {                        // prefetch next chunk's inputs
      u_n = U[ub + (size_t)64 * 4096];
      p_n = P[pb + (size_t)64 * 64];
    }
    U[ub] = f2bf(S);                         // chunk-start state (S_start)
    S = __builtin_fmaf(p_c, S, bf2f(u_c));
    u_c = u_n; p_c = p_n;
    ub += (size_t)64 * 4096;
    pb += (size_t)64 * 64;
  }
  stateOut[(size_t)bh * 4096 + el] = S;   // final state (output 1)
}

// ---------------- phase 3: re-run chunk from true initial state, emit outputs ----------------
// grid (NC, 64 chains), 256 threads = 4 waves; wave w owns d in [16w,16w+16).
// bf16 op/kp/rp/vv staged per window (double-buffered); bf16 partials in LDS;
// block reduces once per 16-step window (2 barriers / 16 steps).
__global__ __launch_bounds__(256) void scan_phase3(const u16* __restrict__ omw,
                                                   const u16* __restrict__ kk,
                                                   const u16* __restrict__ vv,
                                                   const u16* __restrict__ rr,
                                                   const u16* __restrict__ S_start,
                                                   u16* __restrict__ outs) {
  __shared__ u16 win[2 * 4096];              // 2 bufs x {op,kp,rp,vv} x 16 x 64 bf16 = 16 KB
  __shared__ u16 part[4][16][64];            // 8 KB
  const int c = blockIdx.x, bh = blockIdx.y;
  const int tid = threadIdx.x;
  const int lane = tid & 63;                 // e
  const int wid = tid >> 6;
  const int dbase = __builtin_amdgcn_readfirstlane(wid << 4);
  const size_t chainBase = (size_t)(bh >> 4) * TT * DD + (size_t)(bh & 15) * HS;
  const size_t base0 = chainBase + (size_t)c * CH * DD;

  auto stage = [&](int buf, int w2) {
#pragma unroll
    for (int j = 0; j < 2; ++j) {
      const int idx = tid + 256 * j;          // [0,512): (a, tt, seg)
      const int a = idx >> 7, rem = idx & 127, tt = rem >> 3, seg = rem & 7;
      const u16* s = (a == 0) ? omw : (a == 1) ? kk : (a == 2) ? rr : vv;
      gload16(s + base0 + (size_t)(w2 * 16 + tt) * DD + seg * 8,
              &win[buf * 4096 + idx * 8]);
    }
  };

  float st[16];
  const u16* __restrict__ Sb = S_start + ((size_t)c * 64 + bh) * 4096;
#pragma unroll
  for (int i = 0; i < 16; ++i) st[i] = bf2f(Sb[(dbase + i) * 64 + lane]);

  stage(0, 0);
  __syncthreads();
  int buf = 0;
  for (int w2 = 0; w2 < CH / 16; ++w2) {
    if (w2 + 1 < CH / 16) stage(buf ^ 1, w2 + 1);
    const u16* wb = &win[buf * 4096];
#pragma unroll
    for (int tt = 0; tt < 16; ++tt) {
      const short8 o8a = *(const short8*)&wb[       tt * 64 + dbase];
      const short8 o8b = *(const short8*)&wb[       tt * 64 + dbase + 8];
      const short8 k8a = *(const short8*)&wb[1024 + tt * 64 + dbase];
      const short8 k8b = *(const short8*)&wb[1024 + tt * 64 + dbase + 8];
      const short8 r8a = *(const short8*)&wb[2048 + tt * 64 + dbase];
      const short8 r8b = *(const short8*)&wb[2048 + tt * 64 + dbase + 8];
      const float ve  = bf2f(wb[3072 + tt * 64 + lane]);
      float a0 = 0.f, a1 = 0.f;
#pragma unroll
      for (int i = 0; i < 8; ++i) {
        st[i]     = __builtin_fmaf(bf2f((u16)o8a[i]), st[i],     bf2f((u16)k8a[i]) * ve);
        a0 = __builtin_fmaf(bf2f((u16)r8a[i]), st[i], a0);
        st[8 + i] = __builtin_fmaf(bf2f((u16)o8b[i]), st[8 + i], bf2f((u16)k8b[i]) * ve);
        a1 = __builtin_fmaf(bf2f((u16)r8b[i]), st[8 + i], a1);
      }
      part[wid][tt][lane] = f2bf(a0 + a1);
    }
    __syncthreads();                          // partials visible; next buf loaded
#pragma unroll
    for (int s = 0; s < 4; ++s) {
      const int tt = wid * 4 + s;
      const float sum = (bf2f(part[0][tt][lane]) + bf2f(part[1][tt][lane])) +
                        (bf2f(part[2][tt][lane]) + bf2f(part[3][tt][lane]));
      outs[base0 + (size_t)(w2 * 16 + tt) * DD + lane] = f2bf(sum);
    }
    __syncthreads();                          // part reusable
    buf ^= 1;
  }
}

extern "C" void kernel_launch(void* const* d_in, const int* in_sizes, int n_in,
                              void* d_out, int out_size, void* d_ws, size_t ws_size,
                              hipStream_t stream) {
  const float* x   = (const float*)d_in[0];
  const float* lng = (const float*)d_in[1];
  const float* lnb = (const float*)d_in[2];
  const float* Wx  = (const float*)d_in[3];
  const float* Ww  = (const float*)d_in[4];
  const float* bw  = (const float*)d_in[5];
  const float* Wk  = (const float*)d_in[6];
  const float* Wv  = (const float*)d_in[7];
  const float* Wr  = (const float*)d_in[8];
  const float* Wo  = (const float*)d_in[9];
  float* out = (float*)d_out;
  char* ws = (char*)d_ws;

  // ---- workspace layout: within the proven 188 MiB round-1 footprint ----
  const size_t SZ_W = (size_t)DD * DD * 2;       // 2 MB bf16 weight
  u16* WxT = (u16*)(ws + 0 * SZ_W);
  u16* WwT = (u16*)(ws + 1 * SZ_W);
  u16* WkT = (u16*)(ws + 2 * SZ_W);
  u16* WvT = (u16*)(ws + 3 * SZ_W);
  u16* WrT = (u16*)(ws + 4 * SZ_W);
  u16* WoT = (u16*)(ws + 5 * SZ_W);
  size_t off = 6 * SZ_W;
  const size_t SZ_ABF = (size_t)ROWS * DD * 2;   // 16 MB bf16 activation
  u16* xn   = (u16*)(ws + off); off += SZ_ABF;
  u16* pbuf = (u16*)(ws + off); off += SZ_ABF;
  u16* outs = (u16*)(ws + off); off += SZ_ABF;
  // scan inputs now bf16 (16 MB each; region previously held f32 versions)
  u16* omw = (u16*)(ws + off); off += SZ_ABF;
  u16* kf  = (u16*)(ws + off); off += SZ_ABF;
  u16* vf  = (u16*)(ws + off); off += SZ_ABF;
  u16* rf  = (u16*)(ws + off); off += SZ_ABF;
  // scan scratch ALIASES dead buffers:
  //  Ubuf bf16 (NC*64*4096*2 = 32 MiB) -> xn+pbuf region (dead after last projection
  //    GEMM; rewritten by ln_kernel every call, so graph-replay safe)
  //  Pbuf fp32 (NC*64*64*4 = 1 MiB)    -> WxT region (dead after GEMM 1)
  u16*   Ubuf = xn;
  float* Pbuf = (float*)WxT;
  (void)ws_size; (void)in_sizes; (void)n_in; (void)out_size;

  dim3 tpb(32, 8), tgrid(32, 32);
  transpose_cast<<<tgrid, tpb, 0, stream>>>(Wx, WxT);
  transpose_cast<<<tgrid, tpb, 0, stream>>>(Ww, WwT);
  transpose_cast<<<tgrid, tpb, 0, stream>>>(Wk, WkT);
  transpose_cast<<<tgrid, tpb, 0, stream>>>(Wv, WvT);
  transpose_cast<<<tgrid, tpb, 0, stream>>>(Wr, WrT);
  transpose_cast<<<tgrid, tpb, 0, stream>>>(Wo, WoT);

  ln_kernel<<<ROWS, 256, 0, stream>>>(x, lng, lnb, xn);

  dim3 ggrid(DD / 128, ROWS / 128), gblk(256);
  // p = xn @ Wx  (bf16)
  gemm_bt<0><<<ggrid, gblk, 0, stream>>>(xn, WxT, nullptr, pbuf, nullptr, ROWS, DD, DD);
  // omw = 1 - sigmoid(p @ Ww + bw)  (bf16)
  gemm_bt<3><<<ggrid, gblk, 0, stream>>>(pbuf, WwT, nullptr, omw, bw, ROWS, DD, DD);
  // k, v (bf16); r = sigmoid (bf16)
  gemm_bt<0><<<ggrid, gblk, 0, stream>>>(xn, WkT, nullptr, kf, nullptr, ROWS, DD, DD);
  gemm_bt<0><<<ggrid, gblk, 0, stream>>>(xn, WvT, nullptr, vf, nullptr, ROWS, DD, DD);
  gemm_bt<2><<<ggrid, gblk, 0, stream>>>(xn, WrT, nullptr, rf, nullptr, ROWS, DD, DD);

  // chunked scan (xn/pbuf/WxT are dead from here on; their memory hosts Ubuf/Pbuf)
  dim3 sgrid(NC, 64);
  scan_phase1<<<sgrid, 256, 0, stream>>>(omw, kf, vf, Ubuf, Pbuf);
  dim3 p2grid(64, 16);
  scan_phase2<<<p2grid, 256, 0, stream>>>(Ubuf, Pbuf, out + (size_t)ROWS * DD);
  scan_phase3<<<sgrid, 256, 0, stream>>>(omw, kf, vf, rf, Ubuf, outs);

  // y = outs @ Wo (f32, first output)
  gemm_bt<1><<<ggrid, gblk, 0, stream>>>(outs, WoT, out, nullptr, nullptr, ROWS, DD, DD);
}